// Round 10
// baseline (63.944 us; speedup 1.0000x reference)
//
#include <hip/hip_runtime.h>
#include <cstdint>

#define IMG_ELEMS 784
#define NIMG_GRP 8                           // images per group (per block-iter)
#define IMG_STRIDE_DW 788                    // 197*16B: aligned, odd superbank
#define STAGE_DW (NIMG_GRP * IMG_STRIDE_DW)  // 6304 dw = 25,216 B per buffer
#define NWAVES 4
#define SCRATCH_DW (NWAVES * 256)            // 4 waves x 64 lanes x 4 f32
#define BLOCKS 512                           // 2 blocks/CU

typedef __attribute__((ext_vector_type(8))) short short8;
typedef __attribute__((ext_vector_type(4))) float f32x4;

union ABu { uint32_t u[4]; short8 v; };

typedef const __attribute__((address_space(1))) void* gp1_t;
typedef __attribute__((address_space(3))) void* lp3_t;

__device__ inline uint32_t pk_bf16(float a, float b) {
    uint32_t r;
    asm("v_cvt_pk_bf16_f32 %0, %1, %2" : "=v"(r) : "v"(a), "v"(b));
    return r;  // lo = bf16(a), hi = bf16(b)
}

// wave `widb` DMA-stages its 2 images of 8-image group `grp` (8 vmcnt events)
__device__ inline void stage_group(const float* __restrict__ x, float* dst,
                                   int grp, int widb, int lane) {
    const float* gsrc = x + (size_t)grp * (NIMG_GRP * IMG_ELEMS);
#pragma unroll
    for (int k = 0; k < 2; ++k) {
        const int im = widb * 2 + k;
        const float* s = gsrc + im * IMG_ELEMS;
        float* d = dst + im * IMG_STRIDE_DW;
#pragma unroll
        for (int j = 0; j < 3; ++j)
            __builtin_amdgcn_global_load_lds((gp1_t)(s + j * 256 + lane * 4),
                                             (lp3_t)(d + j * 256), 16, 0, 0);
        if (lane < 4)
            __builtin_amdgcn_global_load_lds((gp1_t)(s + 768 + lane * 4),
                                             (lp3_t)(d + 768), 16, 0, 0);
    }
}

__global__ __launch_bounds__(256, 2) void fused_digit_tbuf_kernel(
    const float* __restrict__ x,
    const float* __restrict__ cw9,
    const float* __restrict__ Wlin,
    const float* __restrict__ bias,
    float* __restrict__ out,
    int ngroups, int gpb)
{
    __shared__ float smem[3 * STAGE_DW + SCRATCH_DW];
    float* const bufs0 = smem;
    float* const bufs1 = smem + STAGE_DW;
    float* const bufs2 = smem + 2 * STAGE_DW;
    float* const scr   = smem + 3 * STAGE_DW;

    const int tid  = threadIdx.x;
    const int lane = tid & 63;
    const int widb = tid >> 6;          // 0..3
    const int rc = lane & 15;           // A-row (image; >=8 garbage) AND D-col
    const int g  = lane >> 4;           // conv output cols 8g..8g+7

    float cw[9];
#pragma unroll
    for (int k = 0; k < 9; ++k) cw[k] = cw9[k];
    const float bv = (rc < 10) ? bias[rc] : 0.0f;

    // K-split over 4 waves: rows 7,7,6,6
    const int R0 = (widb < 2) ? 7 * widb : 14 + 6 * (widb - 2);
    const int RC = (widb < 2) ? 7 : 6;

    // W B-fragments for this wave's conv rows (28 VGPRs)
    ABu bf[7];
#pragma unroll
    for (int rr = 0; rr < 7; ++rr) {
        const int r = R0 + rr;
#pragma unroll
        for (int m = 0; m < 4; ++m) {
            const int c0 = 8 * g + 2 * m;
            const int c1 = c0 + 1;
            const bool v0 = (rr < RC) && (c0 < 26) && (rc < 10);
            const bool v1 = (rr < RC) && (c1 < 26) && (rc < 10);
            const float w0 = v0 ? Wlin[(r * 26 + c0) * 10 + rc] : 0.0f;
            const float w1 = v1 ? Wlin[(r * 26 + c1) * 10 + rc] : 0.0f;
            bf[rr].u[m] = pk_bf16(w0, w1);
        }
    }

    // per-lane col offsets, clamped; duplicate data hits zero B-weights
    const int co0 = 8 * g;
    const int co1 = (8 * g + 4 > 24) ? 24 : 8 * g + 4;
    const int co2 = (8 * g + 8 > 24) ? 24 : 8 * g + 8;

    const int gstart = blockIdx.x * gpb;

    // prologue: 2 groups in flight
    if (gstart < ngroups)     stage_group(x, bufs0, gstart,     widb, lane);
    if (gstart + 1 < ngroups && gpb > 1)
                              stage_group(x, bufs1, gstart + 1, widb, lane);

    for (int i = 0; i < gpb; ++i) {
        const int grp = gstart + i;
        if (grp >= ngroups) break;   // block-uniform

        const int ci = i % 3;
        float* const cur = (ci == 0) ? bufs0 : (ci == 1) ? bufs1 : bufs2;
        const int ai = (i + 2) % 3;
        float* const alt = (ai == 0) ? bufs0 : (ai == 1) ? bufs1 : bufs2;

        // keep 2 groups in flight; wait only for group i (issued 2 iters ago)
        if (i + 2 < gpb && grp + 2 < ngroups) {
            stage_group(x, alt, grp + 2, widb, lane);
            asm volatile("s_waitcnt vmcnt(16)" ::: "memory");
        } else if (i + 1 < gpb && grp + 1 < ngroups) {
            asm volatile("s_waitcnt vmcnt(8)" ::: "memory");
        } else {
            asm volatile("s_waitcnt vmcnt(0)" ::: "memory");
        }
        __builtin_amdgcn_s_barrier();        // raw: prefetch stays in flight
        __builtin_amdgcn_sched_barrier(0);

        // ---- conv rows [R0, R0+RC) of image rc, cols 8g..8g+7, f32 ----
        const float* ib = cur + rc * IMG_STRIDE_DW;   // rc>=8: finite garbage
        float accr[3][8];
#pragma unroll
        for (int s = 0; s < 3; ++s)
#pragma unroll
            for (int j = 0; j < 8; ++j) accr[s][j] = 0.0f;
        f32x4 acc = {0.f, 0.f, 0.f, 0.f};

#pragma unroll
        for (int t = 0; t < 9; ++t) {          // input rows R0+t, t < RC+2
            if (t < RC + 2) {
                const float* rp = ib + (R0 + t) * 28;
                float in[12];
                *(float4*)&in[0] = *(const float4*)(rp + co0);
                *(float4*)&in[4] = *(const float4*)(rp + co1);
                *(float4*)&in[8] = *(const float4*)(rp + co2);

                const int s0 = t % 3;
                const int s1 = (t + 2) % 3;
                const int s2 = (t + 1) % 3;

                if (t < RC) {
#pragma unroll
                    for (int j = 0; j < 8; ++j)
                        accr[s0][j] = fmaf(in[j], cw[0],
                                      fmaf(in[j + 1], cw[1],
                                      fmaf(in[j + 2], cw[2], accr[s0][j])));
                }
                if (t >= 1 && t <= RC) {
#pragma unroll
                    for (int j = 0; j < 8; ++j)
                        accr[s1][j] = fmaf(in[j], cw[3],
                                      fmaf(in[j + 1], cw[4],
                                      fmaf(in[j + 2], cw[5], accr[s1][j])));
                }
                if (t >= 2) {
#pragma unroll
                    for (int j = 0; j < 8; ++j)
                        accr[s2][j] = fmaf(in[j], cw[6],
                                      fmaf(in[j + 1], cw[7],
                                      fmaf(in[j + 2], cw[8], accr[s2][j])));
                    ABu a;
#pragma unroll
                    for (int m = 0; m < 4; ++m)
                        a.u[m] = pk_bf16(fmaxf(accr[s2][2 * m], 0.f),
                                         fmaxf(accr[s2][2 * m + 1], 0.f));
                    acc = __builtin_amdgcn_mfma_f32_16x16x32_bf16(
                              a.v, bf[t - 2].v, acc, 0, 0, 0);
#pragma unroll
                    for (int j = 0; j < 8; ++j) accr[s2][j] = 0.0f;
                }
            }
        }

        // ---- cross-wave K-reduction ----
        *reinterpret_cast<f32x4*>(scr + widb * 256 + lane * 4) = acc;
        asm volatile("s_waitcnt lgkmcnt(0)" ::: "memory");
        __builtin_amdgcn_s_barrier();        // raw: prefetch stays in flight
        __builtin_amdgcn_sched_barrier(0);

        if (widb == (i & 3)) {   // rotate reducer
            const float* sp = scr + lane * 4;
            float s[4] = {0.f, 0.f, 0.f, 0.f};
#pragma unroll
            for (int w = 0; w < NWAVES; ++w) {
                f32x4 p = *reinterpret_cast<const f32x4*>(sp + w * 256);
#pragma unroll
                for (int q = 0; q < 4; ++q) s[q] += p[q];
            }
            // D rows 0..7 = images (g<2); rows 8..15 garbage -> skip
            if (rc < 10 && g < 2) {
                float* po = out + ((size_t)grp * NIMG_GRP + (size_t)g * 4) * 10 + rc;
#pragma unroll
                for (int q = 0; q < 4; ++q) po[q * 10] = s[q] + bv;
            }
        }
    }
}

extern "C" void kernel_launch(void* const* d_in, const int* in_sizes, int n_in,
                              void* d_out, int out_size, void* d_ws, size_t ws_size,
                              hipStream_t stream) {
    const float* x   = (const float*)d_in[0];
    const float* cw  = (const float*)d_in[1];
    const float* W   = (const float*)d_in[2];
    const float* b   = (const float*)d_in[3];
    float* out = (float*)d_out;

    const int nimg    = in_sizes[0] / IMG_ELEMS;
    const int ngroups = nimg / NIMG_GRP;                  // 8192
    const int gpb     = (ngroups + BLOCKS - 1) / BLOCKS;  // 16

    hipLaunchKernelGGL(fused_digit_tbuf_kernel, dim3(BLOCKS), dim3(256), 0, stream,
                       x, cw, W, b, out, ngroups, gpb);
}

// Round 11
// 56.809 us; speedup vs baseline: 1.1256x; 1.1256x over previous
//
#include <hip/hip_runtime.h>
#include <cstdint>

#define IMG_ELEMS 784
#define NIMG_GRP 16
#define IMG_STRIDE_DW 788                    // 197*16B: aligned, odd superbank
#define STAGE_DW (NIMG_GRP * IMG_STRIDE_DW)  // 12,608 dw = 50,432 B
#define NWAVES 4
#define SCRATCH_DW (NWAVES * 256)            // 1024 dw = 4 KB (single-buffered)
#define BLOCKS 768                           // 3 blocks/CU x 256 CU

typedef __attribute__((ext_vector_type(8))) short short8;
typedef __attribute__((ext_vector_type(4))) float f32x4;

union ABu { uint32_t u[4]; short8 v; };

typedef const __attribute__((address_space(1))) void* gp1_t;
typedef __attribute__((address_space(3))) void* lp3_t;

__device__ inline uint32_t pk_bf16(float a, float b) {
    uint32_t r;
    asm("v_cvt_pk_bf16_f32 %0, %1, %2" : "=v"(r) : "v"(a), "v"(b));
    return r;  // lo = bf16(a), hi = bf16(b)
}

// wave `widb` DMA-stages its 4 images of group `grp` into LDS (f32, coalesced)
__device__ inline void stage_group(const float* __restrict__ x, float* stage,
                                   int grp, int widb, int lane) {
    const float* gsrc = x + (size_t)grp * (NIMG_GRP * IMG_ELEMS);
#pragma unroll
    for (int k = 0; k < 4; ++k) {
        const int im = widb * 4 + k;
        const float* s = gsrc + im * IMG_ELEMS;
        float* dbase = stage + im * IMG_STRIDE_DW;
#pragma unroll
        for (int j = 0; j < 3; ++j)
            __builtin_amdgcn_global_load_lds((gp1_t)(s + j * 256 + lane * 4),
                                             (lp3_t)(dbase + j * 256), 16, 0, 0);
        if (lane < 4)
            __builtin_amdgcn_global_load_lds((gp1_t)(s + 768 + lane * 4),
                                             (lp3_t)(dbase + 768), 16, 0, 0);
    }
}

__global__ __launch_bounds__(256, 3) void fused_digit_dma3_kernel(
    const float* __restrict__ x,
    const float* __restrict__ cw9,
    const float* __restrict__ Wlin,
    const float* __restrict__ bias,
    float* __restrict__ out,
    int ngroups)
{
    __shared__ float smem[STAGE_DW + SCRATCH_DW];
    float* const stagebuf = smem;
    float* const scr      = smem + STAGE_DW;

    const int tid  = threadIdx.x;
    const int lane = tid & 63;
    const int widb = tid >> 6;          // 0..3
    const int rc = lane & 15;           // A-row (image) AND D-col (class)
    const int g  = lane >> 4;           // conv output cols 8g..8g+7

    float cw[9];
#pragma unroll
    for (int k = 0; k < 9; ++k) cw[k] = cw9[k];
    const float bv = (rc < 10) ? bias[rc] : 0.0f;

    // K-split: wave widb owns conv output rows [R0, R0+RC)  (7,7,6,6)
    const int R0 = (widb < 2) ? widb * 7 : 14 + (widb - 2) * 6;
    const int RC = (widb < 2) ? 7 : 6;

    // W B-fragments for this wave's rows (28 VGPRs)
    ABu bf[7];
#pragma unroll
    for (int rr = 0; rr < 7; ++rr) {
        const int r = R0 + rr;
#pragma unroll
        for (int m = 0; m < 4; ++m) {
            const int c0 = 8 * g + 2 * m;
            const int c1 = c0 + 1;
            const bool v0 = (rr < RC) && (c0 < 26) && (rc < 10);
            const bool v1 = (rr < RC) && (c1 < 26) && (rc < 10);
            const float w0 = v0 ? Wlin[(r * 26 + c0) * 10 + rc] : 0.0f;
            const float w1 = v1 ? Wlin[(r * 26 + c1) * 10 + rc] : 0.0f;
            bf[rr].u[m] = pk_bf16(w0, w1);
        }
    }

    // per-lane col offsets (floats), clamped; dup data hits zero B-weights
    const int co0 = 8 * g;
    const int co1 = (8 * g + 4 > 24) ? 24 : 8 * g + 4;
    const int co2 = (8 * g + 8 > 24) ? 24 : 8 * g + 8;

    // interleaved mapping: block b handles groups b, b+grid, b+2*grid, ...
    // (balanced 5-6 groups/block; adjacent blocks stream adjacent memory)
    if (blockIdx.x < (unsigned)ngroups)
        stage_group(x, stagebuf, blockIdx.x, widb, lane);

    for (int grp = blockIdx.x; grp < ngroups; grp += gridDim.x) {

        asm volatile("s_waitcnt vmcnt(0)" ::: "memory");  // own DMA done
        __syncthreads();                                  // everyone's DMA done

        // ---- conv rows [R0, R0+RC) of image rc, cols 8g..8g+7, f32 ----
        const float* ib = stagebuf + rc * IMG_STRIDE_DW;
        float accr[3][8];
#pragma unroll
        for (int s = 0; s < 3; ++s)
#pragma unroll
            for (int j = 0; j < 8; ++j) accr[s][j] = 0.0f;
        f32x4 acc = {0.f, 0.f, 0.f, 0.f};

#pragma unroll
        for (int t = 0; t < 9; ++t) {          // input rows R0+t, t < RC+2
            if (t < RC + 2) {
                const float* rp = ib + (R0 + t) * 28;
                float in[12];
                *(float4*)&in[0] = *(const float4*)(rp + co0);
                *(float4*)&in[4] = *(const float4*)(rp + co1);
                *(float4*)&in[8] = *(const float4*)(rp + co2);

                const int s0 = t % 3;          // out row t   (kernel row 0)
                const int s1 = (t + 2) % 3;    // out row t-1 (kernel row 1)
                const int s2 = (t + 1) % 3;    // out row t-2 (kernel row 2)

                if (t < RC) {
#pragma unroll
                    for (int j = 0; j < 8; ++j)
                        accr[s0][j] = fmaf(in[j], cw[0],
                                      fmaf(in[j + 1], cw[1],
                                      fmaf(in[j + 2], cw[2], accr[s0][j])));
                }
                if (t >= 1 && t <= RC) {
#pragma unroll
                    for (int j = 0; j < 8; ++j)
                        accr[s1][j] = fmaf(in[j], cw[3],
                                      fmaf(in[j + 1], cw[4],
                                      fmaf(in[j + 2], cw[5], accr[s1][j])));
                }
                if (t >= 2) {
#pragma unroll
                    for (int j = 0; j < 8; ++j)
                        accr[s2][j] = fmaf(in[j], cw[6],
                                      fmaf(in[j + 1], cw[7],
                                      fmaf(in[j + 2], cw[8], accr[s2][j])));
                    ABu a;
#pragma unroll
                    for (int m = 0; m < 4; ++m)
                        a.u[m] = pk_bf16(fmaxf(accr[s2][2 * m], 0.f),
                                         fmaxf(accr[s2][2 * m + 1], 0.f));
                    acc = __builtin_amdgcn_mfma_f32_16x16x32_bf16(
                              a.v, bf[t - 2].v, acc, 0, 0, 0);
#pragma unroll
                    for (int j = 0; j < 8; ++j) accr[s2][j] = 0.0f;
                }
            }
        }

        // ---- cross-wave K-reduction (single scratch: safe, see barrier order) ----
        *reinterpret_cast<f32x4*>(scr + widb * 256 + lane * 4) = acc;
        __syncthreads();   // conv reads of stagebuf done + scratch visible

        // buffer free: immediately start next group's DMA (overlaps reduce +
        // other blocks' conv phases — 3 blocks/CU give ~1.8x DMA coverage)
        const int nxt = grp + gridDim.x;
        if (nxt < ngroups) stage_group(x, stagebuf, nxt, widb, lane);

        if (widb == (grp & 3)) {   // rotate reducer to spread the cost
            const float* sp = scr + lane * 4;
            f32x4 p0 = *reinterpret_cast<const f32x4*>(sp);
            f32x4 p1 = *reinterpret_cast<const f32x4*>(sp + 256);
            f32x4 p2 = *reinterpret_cast<const f32x4*>(sp + 512);
            f32x4 p3 = *reinterpret_cast<const f32x4*>(sp + 768);
            if (rc < 10) {
                float* po = out + ((size_t)grp * NIMG_GRP + (size_t)g * 4) * 10 + rc;
#pragma unroll
                for (int q = 0; q < 4; ++q)
                    po[q * 10] = p0[q] + p1[q] + p2[q] + p3[q] + bv;
            }
        }
    }
}

extern "C" void kernel_launch(void* const* d_in, const int* in_sizes, int n_in,
                              void* d_out, int out_size, void* d_ws, size_t ws_size,
                              hipStream_t stream) {
    const float* x   = (const float*)d_in[0];
    const float* cw  = (const float*)d_in[1];
    const float* W   = (const float*)d_in[2];
    const float* b   = (const float*)d_in[3];
    float* out = (float*)d_out;

    const int nimg    = in_sizes[0] / IMG_ELEMS;
    const int ngroups = nimg / NIMG_GRP;   // 4096

    hipLaunchKernelGGL(fused_digit_dma3_kernel, dim3(BLOCKS), dim3(256), 0, stream,
                       x, cw, W, b, out, ngroups);
}

// Round 12
// 50.582 us; speedup vs baseline: 1.2642x; 1.1231x over previous
//
#include <hip/hip_runtime.h>
#include <cstdint>

#define IMG_ELEMS 784
#define NIMG_GRP 16
#define IMG_STRIDE_DW 788                    // 197*16B: aligned, odd superbank
#define STAGE_DW (NIMG_GRP * IMG_STRIDE_DW)  // 12,608 dw = 50,432 B per buffer
#define NWAVES 8
#define SCRATCH_DW (NWAVES * 256)            // 8 waves x 64 lanes x 4 f32
#define BLOCKS 256                           // 1 block/CU; gpb = 16 uniform

typedef __attribute__((ext_vector_type(8))) short short8;
typedef __attribute__((ext_vector_type(4))) float f32x4;

union ABu { uint32_t u[4]; short8 v; };

typedef const __attribute__((address_space(1))) void* gp1_t;
typedef __attribute__((address_space(3))) void* lp3_t;

__device__ inline uint32_t pk_bf16(float a, float b) {
    uint32_t r;
    asm("v_cvt_pk_bf16_f32 %0, %1, %2" : "=v"(r) : "v"(a), "v"(b));
    return r;  // lo = bf16(a), hi = bf16(b)
}

// wave `widb` DMA-stages its 2 images of group `grp` (exactly 8 vmcnt events)
__device__ inline void stage_group(const float* __restrict__ x, float* dst,
                                   int grp, int widb, int lane) {
    const float* gsrc = x + (size_t)grp * (NIMG_GRP * IMG_ELEMS);
#pragma unroll
    for (int k = 0; k < 2; ++k) {
        const int im = widb * 2 + k;
        const float* s = gsrc + im * IMG_ELEMS;
        float* d = dst + im * IMG_STRIDE_DW;
#pragma unroll
        for (int j = 0; j < 3; ++j)
            __builtin_amdgcn_global_load_lds((gp1_t)(s + j * 256 + lane * 4),
                                             (lp3_t)(d + j * 256), 16, 0, 0);
        if (lane < 4)
            __builtin_amdgcn_global_load_lds((gp1_t)(s + 768 + lane * 4),
                                             (lp3_t)(d + 768), 16, 0, 0);
    }
}

__global__ __launch_bounds__(512, 1) void fused_digit_d2_kernel(
    const float* __restrict__ x,
    const float* __restrict__ cw9,
    const float* __restrict__ Wlin,
    const float* __restrict__ bias,
    float* __restrict__ out,
    int ngroups, int gpb)
{
    __shared__ float smem[3 * STAGE_DW + SCRATCH_DW];
    float* const buf0 = smem;
    float* const buf1 = smem + STAGE_DW;
    float* const buf2 = smem + 2 * STAGE_DW;
    float* const scr  = smem + 3 * STAGE_DW;

    const int tid  = threadIdx.x;
    const int lane = tid & 63;
    const int widb = tid >> 6;          // 0..7
    const int rc = lane & 15;           // A-row (image) AND D-col (class)
    const int g  = lane >> 4;           // conv output cols 8g..8g+7

    float cw[9];
#pragma unroll
    for (int k = 0; k < 9; ++k) cw[k] = cw9[k];
    const float bv = (rc < 10) ? bias[rc] : 0.0f;

    // K-split over 8 waves: rows 4,4,3,3,3,3,3,3
    const int R0 = (widb < 2) ? 4 * widb : 8 + 3 * (widb - 2);
    const int RC = (widb < 2) ? 4 : 3;

    // W B-fragments for this wave's conv rows (16 VGPRs)
    ABu bf[4];
#pragma unroll
    for (int rr = 0; rr < 4; ++rr) {
        const int r = R0 + rr;
#pragma unroll
        for (int m = 0; m < 4; ++m) {
            const int c0 = 8 * g + 2 * m;
            const int c1 = c0 + 1;
            const bool v0 = (rr < RC) && (c0 < 26) && (rc < 10);
            const bool v1 = (rr < RC) && (c1 < 26) && (rc < 10);
            const float w0 = v0 ? Wlin[(r * 26 + c0) * 10 + rc] : 0.0f;
            const float w1 = v1 ? Wlin[(r * 26 + c1) * 10 + rc] : 0.0f;
            bf[rr].u[m] = pk_bf16(w0, w1);
        }
    }

    // per-lane col offsets, clamped; duplicate data hits zero B-weights
    const int co0 = 8 * g;
    const int co1 = (8 * g + 4 > 24) ? 24 : 8 * g + 4;
    const int co2 = (8 * g + 8 > 24) ? 24 : 8 * g + 8;

    const int gstart = blockIdx.x * gpb;

    // prologue: TWO groups in flight (depth-2 -> ~25 MB outstanding chip-wide)
    if (gstart < ngroups)                  stage_group(x, buf0, gstart,     widb, lane);
    if (gpb > 1 && gstart + 1 < ngroups)   stage_group(x, buf1, gstart + 1, widb, lane);

    for (int i = 0; i < gpb; ++i) {
        const int grp = gstart + i;
        if (grp >= ngroups) break;   // block-uniform (gpb exact for B=65536)

        const int ci = i % 3;
        float* const cur = (ci == 0) ? buf0 : (ci == 1) ? buf1 : buf2;
        const int ai = (i + 2) % 3;
        float* const alt = (ai == 0) ? buf0 : (ai == 1) ? buf1 : buf2;

        // keep 2 groups ahead in flight; wait only for group i
        // (its 8 loads were issued 2 iterations ago)
        if (i + 2 < gpb && grp + 2 < ngroups) {
            stage_group(x, alt, grp + 2, widb, lane);
            asm volatile("s_waitcnt vmcnt(16)" ::: "memory");
        } else if (i + 1 < gpb && grp + 1 < ngroups) {
            asm volatile("s_waitcnt vmcnt(8)" ::: "memory");
        } else {
            asm volatile("s_waitcnt vmcnt(0)" ::: "memory");
        }
        __builtin_amdgcn_s_barrier();        // raw: prefetch stays in flight
        __builtin_amdgcn_sched_barrier(0);

        // ---- conv rows [R0, R0+RC) of image rc, cols 8g..8g+7, f32 ----
        const float* ib = cur + rc * IMG_STRIDE_DW;
        float accr[3][8];
#pragma unroll
        for (int s = 0; s < 3; ++s)
#pragma unroll
            for (int j = 0; j < 8; ++j) accr[s][j] = 0.0f;
        f32x4 acc = {0.f, 0.f, 0.f, 0.f};

#pragma unroll
        for (int t = 0; t < 6; ++t) {          // input rows R0+t, t < RC+2
            if (t < RC + 2) {
                const float* rp = ib + (R0 + t) * 28;
                float in[12];
                *(float4*)&in[0] = *(const float4*)(rp + co0);
                *(float4*)&in[4] = *(const float4*)(rp + co1);
                *(float4*)&in[8] = *(const float4*)(rp + co2);

                const int s0 = t % 3;
                const int s1 = (t + 2) % 3;
                const int s2 = (t + 1) % 3;

                if (t < RC) {
#pragma unroll
                    for (int j = 0; j < 8; ++j)
                        accr[s0][j] = fmaf(in[j], cw[0],
                                      fmaf(in[j + 1], cw[1],
                                      fmaf(in[j + 2], cw[2], accr[s0][j])));
                }
                if (t >= 1 && t <= RC) {
#pragma unroll
                    for (int j = 0; j < 8; ++j)
                        accr[s1][j] = fmaf(in[j], cw[3],
                                      fmaf(in[j + 1], cw[4],
                                      fmaf(in[j + 2], cw[5], accr[s1][j])));
                }
                if (t >= 2) {
#pragma unroll
                    for (int j = 0; j < 8; ++j)
                        accr[s2][j] = fmaf(in[j], cw[6],
                                      fmaf(in[j + 1], cw[7],
                                      fmaf(in[j + 2], cw[8], accr[s2][j])));
                    ABu a;
#pragma unroll
                    for (int m = 0; m < 4; ++m)
                        a.u[m] = pk_bf16(fmaxf(accr[s2][2 * m], 0.f),
                                         fmaxf(accr[s2][2 * m + 1], 0.f));
                    acc = __builtin_amdgcn_mfma_f32_16x16x32_bf16(
                              a.v, bf[t - 2].v, acc, 0, 0, 0);
#pragma unroll
                    for (int j = 0; j < 8; ++j) accr[s2][j] = 0.0f;
                }
            }
        }

        // ---- cross-wave K-reduction ----
        *reinterpret_cast<f32x4*>(scr + widb * 256 + lane * 4) = acc;
        asm volatile("s_waitcnt lgkmcnt(0)" ::: "memory");
        __builtin_amdgcn_s_barrier();        // raw: prefetch stays in flight
        __builtin_amdgcn_sched_barrier(0);

        if (widb == (i & 7)) {   // rotate reducer
            const float* sp = scr + lane * 4;
            float s[4] = {0.f, 0.f, 0.f, 0.f};
#pragma unroll
            for (int w = 0; w < NWAVES; ++w) {
                f32x4 p = *reinterpret_cast<const f32x4*>(sp + w * 256);
#pragma unroll
                for (int q = 0; q < 4; ++q) s[q] += p[q];
            }
            if (rc < 10) {
                float* po = out + ((size_t)grp * NIMG_GRP + (size_t)g * 4) * 10 + rc;
#pragma unroll
                for (int q = 0; q < 4; ++q) po[q * 10] = s[q] + bv;
            }
        }
    }
}

extern "C" void kernel_launch(void* const* d_in, const int* in_sizes, int n_in,
                              void* d_out, int out_size, void* d_ws, size_t ws_size,
                              hipStream_t stream) {
    const float* x   = (const float*)d_in[0];
    const float* cw  = (const float*)d_in[1];
    const float* W   = (const float*)d_in[2];
    const float* b   = (const float*)d_in[3];
    float* out = (float*)d_out;

    const int nimg    = in_sizes[0] / IMG_ELEMS;
    const int ngroups = nimg / NIMG_GRP;                  // 4096
    const int gpb     = (ngroups + BLOCKS - 1) / BLOCKS;  // 16, exact

    hipLaunchKernelGGL(fused_digit_d2_kernel, dim3(BLOCKS), dim3(512), 0, stream,
                       x, cw, W, b, out, ngroups, gpb);
}

// Round 13
// 45.991 us; speedup vs baseline: 1.3904x; 1.0998x over previous
//
#include <hip/hip_runtime.h>
#include <cstdint>

#define IMG_ELEMS 784
#define NIMG_GRP 16
#define IMG_STRIDE_DW 788                    // 197*16B: aligned, odd superbank
#define STAGE_DW (NIMG_GRP * IMG_STRIDE_DW)  // 12,608 dw = 50,432 B
#define SCRATCH_DW 2048                      // dbuf: 2 x (4 waves x 64 lanes x 4 f32)
#define BLOCKS 512                           // 2 blocks/CU x 256 CU

typedef __attribute__((ext_vector_type(8))) short short8;
typedef __attribute__((ext_vector_type(4))) float f32x4;

union ABu { uint32_t u[4]; short8 v; };

typedef const __attribute__((address_space(1))) void* gp1_t;
typedef __attribute__((address_space(3))) void* lp3_t;

__device__ inline uint32_t pk_bf16(float a, float b) {
    uint32_t r;
    asm("v_cvt_pk_bf16_f32 %0, %1, %2" : "=v"(r) : "v"(a), "v"(b));
    return r;  // lo = bf16(a), hi = bf16(b)
}

// wave `widb` DMA-stages its 4 images of group `grp` into LDS (f32, coalesced)
__device__ inline void stage_group(const float* __restrict__ x, float* stage,
                                   int grp, int widb, int lane) {
    const float* gsrc = x + (size_t)grp * (NIMG_GRP * IMG_ELEMS);
#pragma unroll
    for (int k = 0; k < 4; ++k) {
        const int im = widb * 4 + k;
        const float* s = gsrc + im * IMG_ELEMS;
        float* dbase = stage + im * IMG_STRIDE_DW;
#pragma unroll
        for (int j = 0; j < 3; ++j) {   // floats [256j, 256j+256)
            __builtin_amdgcn_global_load_lds((gp1_t)(s + j * 256 + lane * 4),
                                             (lp3_t)(dbase + j * 256), 16, 0, 0);
        }
        if (lane < 4) {                 // tail floats 768..783
            __builtin_amdgcn_global_load_lds((gp1_t)(s + 768 + lane * 4),
                                             (lp3_t)(dbase + 768), 16, 0, 0);
        }
    }
}

__global__ __launch_bounds__(256, 2) void fused_digit_dma_kernel(
    const float* __restrict__ x,
    const float* __restrict__ cw9,
    const float* __restrict__ Wlin,
    const float* __restrict__ bias,
    float* __restrict__ out,
    int ngroups, int grp_per_blk)
{
    __shared__ float smem[STAGE_DW + SCRATCH_DW];
    float* stagebuf = smem;

    const int tid  = threadIdx.x;
    const int lane = tid & 63;
    const int widb = tid >> 6;
    const int rc = lane & 15;   // A-row (image) AND D-col (class)
    const int g  = lane >> 4;   // conv output cols 8g..8g+7

    // uniform conv weights + bias
    float cw[9];
#pragma unroll
    for (int k = 0; k < 9; ++k) cw[k] = cw9[k];
    const float bv = (rc < 10) ? bias[rc] : 0.0f;

    // K-split: wave widb owns conv output rows [R0, R0+RC)  (7,7,6,6)
    const int R0 = (widb < 2) ? widb * 7 : 14 + (widb - 2) * 6;
    const int RC = (widb < 2) ? 7 : 6;

    // W B-fragments for this wave's rows (28 VGPRs)
    ABu bf[7];
#pragma unroll
    for (int rr = 0; rr < 7; ++rr) {
        const int r = R0 + rr;
#pragma unroll
        for (int m = 0; m < 4; ++m) {
            const int c0 = 8 * g + 2 * m;
            const int c1 = c0 + 1;
            const bool v0 = (rr < RC) && (c0 < 26) && (rc < 10);
            const bool v1 = (rr < RC) && (c1 < 26) && (rc < 10);
            const float w0 = v0 ? Wlin[(r * 26 + c0) * 10 + rc] : 0.0f;
            const float w1 = v1 ? Wlin[(r * 26 + c1) * 10 + rc] : 0.0f;
            bf[rr].u[m] = pk_bf16(w0, w1);
        }
    }

    // per-lane col offsets (floats), clamped; dup data hits zero B-weights
    const int co0 = 8 * g;
    const int co1 = (8 * g + 4 > 24) ? 24 : 8 * g + 4;
    const int co2 = (8 * g + 8 > 24) ? 24 : 8 * g + 8;

    const int gstart = blockIdx.x * grp_per_blk;

    // prologue: stage first group
    if (gstart < ngroups) stage_group(x, stagebuf, gstart, widb, lane);

    for (int i = 0; i < grp_per_blk; ++i) {
        const int grp = gstart + i;
        if (grp >= ngroups) break;   // block-uniform

        asm volatile("s_waitcnt vmcnt(0)" ::: "memory");  // own DMA done
        __syncthreads();                                  // everyone's DMA done

        // ---- conv rows [R0, R0+RC) of image rc, cols 8g..8g+7, f32 ----
        const float* ib = &stagebuf[rc * IMG_STRIDE_DW];
        float accr[3][8];
#pragma unroll
        for (int s = 0; s < 3; ++s)
#pragma unroll
            for (int j = 0; j < 8; ++j) accr[s][j] = 0.0f;
        f32x4 acc = {0.f, 0.f, 0.f, 0.f};

#pragma unroll
        for (int t = 0; t < 9; ++t) {          // input rows R0+t
            if (t < RC + 2) {
                const float* rp = ib + (R0 + t) * 28;
                float in[12];
                *(float4*)&in[0] = *(const float4*)(rp + co0);
                *(float4*)&in[4] = *(const float4*)(rp + co1);
                *(float4*)&in[8] = *(const float4*)(rp + co2);

                const int s0 = t % 3;          // out row t   (kernel row 0)
                const int s1 = (t + 2) % 3;    // out row t-1 (kernel row 1)
                const int s2 = (t + 1) % 3;    // out row t-2 (kernel row 2)

                if (t < RC) {
#pragma unroll
                    for (int j = 0; j < 8; ++j)
                        accr[s0][j] = fmaf(in[j], cw[0],
                                      fmaf(in[j + 1], cw[1],
                                      fmaf(in[j + 2], cw[2], accr[s0][j])));
                }
                if (t >= 1 && t <= RC) {
#pragma unroll
                    for (int j = 0; j < 8; ++j)
                        accr[s1][j] = fmaf(in[j], cw[3],
                                      fmaf(in[j + 1], cw[4],
                                      fmaf(in[j + 2], cw[5], accr[s1][j])));
                }
                if (t >= 2) {
#pragma unroll
                    for (int j = 0; j < 8; ++j)
                        accr[s2][j] = fmaf(in[j], cw[6],
                                      fmaf(in[j + 1], cw[7],
                                      fmaf(in[j + 2], cw[8], accr[s2][j])));
                    // local output row o = t-2 complete
                    ABu a;
#pragma unroll
                    for (int m = 0; m < 4; ++m)
                        a.u[m] = pk_bf16(fmaxf(accr[s2][2 * m], 0.f),
                                         fmaxf(accr[s2][2 * m + 1], 0.f));
                    acc = __builtin_amdgcn_mfma_f32_16x16x32_bf16(
                              a.v, bf[t - 2].v, acc, 0, 0, 0);
#pragma unroll
                    for (int j = 0; j < 8; ++j) accr[s2][j] = 0.0f;
                }
            }
        }

        // ---- cross-wave K-reduction (double-buffered scratch) ----
        float* sc = &smem[STAGE_DW + (i & 1) * 1024];
        *reinterpret_cast<f32x4*>(sc + widb * 256 + lane * 4) = acc;
        __syncthreads();   // conv reads done + scratch visible

        // buffer free: start next group's DMA immediately (overlaps reduce
        // and the co-resident block's conv phase)
        if (i + 1 < grp_per_blk && grp + 1 < ngroups)
            stage_group(x, stagebuf, grp + 1, widb, lane);

        if (widb == (i & 3)) {   // rotate reducer to spread the tail cost
            const float* scr = sc + lane * 4;
            f32x4 s0 = *reinterpret_cast<const f32x4*>(scr);
            f32x4 s1 = *reinterpret_cast<const f32x4*>(scr + 256);
            f32x4 s2 = *reinterpret_cast<const f32x4*>(scr + 512);
            f32x4 s3 = *reinterpret_cast<const f32x4*>(scr + 768);
            if (rc < 10) {
                float* po = out + ((size_t)grp * NIMG_GRP + (size_t)g * 4) * 10 + rc;
#pragma unroll
                for (int q = 0; q < 4; ++q)
                    po[q * 10] = s0[q] + s1[q] + s2[q] + s3[q] + bv;
            }
        }
    }
}

extern "C" void kernel_launch(void* const* d_in, const int* in_sizes, int n_in,
                              void* d_out, int out_size, void* d_ws, size_t ws_size,
                              hipStream_t stream) {
    const float* x   = (const float*)d_in[0];
    const float* cw  = (const float*)d_in[1];
    const float* W   = (const float*)d_in[2];
    const float* b   = (const float*)d_in[3];
    float* out = (float*)d_out;

    const int nimg    = in_sizes[0] / IMG_ELEMS;
    const int ngroups = nimg / NIMG_GRP;                  // 4096
    const int gpb     = (ngroups + BLOCKS - 1) / BLOCKS;  // 8 for B=65536

    hipLaunchKernelGGL(fused_digit_dma_kernel, dim3(BLOCKS), dim3(256), 0, stream,
                       x, cw, W, b, out, ngroups, gpb);
}